// Round 2
// baseline (636.589 us; speedup 1.0000x reference)
//
#include <hip/hip_runtime.h>
#include <hip/hip_fp16.h>
#include <math.h>

#define TOK   8192
#define DIN   2048
#define DOUT  2048
#define DPROJ 512
#define NEXP  8
#define CAP   8192

typedef _Float16 f16;
typedef _Float16 f16x8 __attribute__((ext_vector_type(8)));
typedef float f32x4 __attribute__((ext_vector_type(4)));

#define AS1C(p) ((const __attribute__((address_space(1))) void*)(p))
#define AS3(p)  ((__attribute__((address_space(3))) void*)(p))

// ---------------- transpose + fp32->f16 convert: W[R][C] -> Wt[C][R] ----------------
__global__ __launch_bounds__(256) void k_transpose(const float* __restrict__ W,
                                                   f16* __restrict__ Wt,
                                                   int R, int C) {
  __shared__ f16 tile[32][33];
  size_t eoff = (size_t)blockIdx.z * R * C;
  const float* We = W + eoff;
  f16* Wte = Wt + eoff;
  int r0 = blockIdx.y * 32, c0 = blockIdx.x * 32;
  int lr = threadIdx.x >> 5;   // 0..7
  int lc = threadIdx.x & 31;
#pragma unroll
  for (int i = 0; i < 4; i++) {
    int r = lr * 4 + i;
    tile[r][lc] = (f16)We[(size_t)(r0 + r) * C + c0 + lc];
  }
  __syncthreads();
#pragma unroll
  for (int i = 0; i < 4; i++) {
    int r = lr * 4 + i;  // output row within tile = input column
    Wte[(size_t)(c0 + r) * R + r0 + lc] = tile[lc][r];
  }
}

// ---------------- routing: gate GEMV + softmax + top2 + 3 lists; also x -> f16 ----------------
// counts layout: [0..7]=all (both choices), [8..15]=first choice, [16..23]=second choice
__global__ __launch_bounds__(256) void k_route(const float* __restrict__ x,
                                               const float* __restrict__ gw,
                                               const float* __restrict__ gb,
                                               f16* __restrict__ xh,
                                               float* __restrict__ ewflat,
                                               int* __restrict__ listAll,
                                               int* __restrict__ listK0,
                                               int* __restrict__ listK1,
                                               int* __restrict__ counts) {
  int t = blockIdx.x;
  int tid = threadIdx.x;
  const float* xr = x + (size_t)t * DIN;
  float4 v0 = ((const float4*)xr)[tid * 2];
  float4 v1 = ((const float4*)xr)[tid * 2 + 1];
  float xv[8] = {v0.x, v0.y, v0.z, v0.w, v1.x, v1.y, v1.z, v1.w};
  f16x8 hv;
#pragma unroll
  for (int j = 0; j < 8; j++) hv[j] = (f16)xv[j];
  *(f16x8*)(xh + (size_t)t * DIN + (size_t)tid * 8) = hv;

  float acc[8] = {0.f, 0.f, 0.f, 0.f, 0.f, 0.f, 0.f, 0.f};
  const float4* gr = (const float4*)(gw + (size_t)tid * 8 * NEXP);
#pragma unroll
  for (int j = 0; j < 8; j++) {
    float4 g0 = gr[j * 2], g1 = gr[j * 2 + 1];
    acc[0] += xv[j] * g0.x; acc[1] += xv[j] * g0.y;
    acc[2] += xv[j] * g0.z; acc[3] += xv[j] * g0.w;
    acc[4] += xv[j] * g1.x; acc[5] += xv[j] * g1.y;
    acc[6] += xv[j] * g1.z; acc[7] += xv[j] * g1.w;
  }
#pragma unroll
  for (int off = 32; off > 0; off >>= 1) {
#pragma unroll
    for (int e = 0; e < 8; e++) acc[e] += __shfl_down(acc[e], off, 64);
  }
  __shared__ float wsum[4][8];
  int lane = tid & 63, wave = tid >> 6;
  if (lane == 0) {
#pragma unroll
    for (int e = 0; e < 8; e++) wsum[wave][e] = acc[e];
  }
  __syncthreads();
  if (tid == 0) {
    const float inv = 0.022097086912079608f;  // 1/sqrt(2048)
    float lg[8];
    float mx = -1e30f;
    for (int e = 0; e < 8; e++) {
      lg[e] = (wsum[0][e] + wsum[1][e] + wsum[2][e] + wsum[3][e] + gb[e]) * inv;
      mx = fmaxf(mx, lg[e]);
    }
    float p[8], se = 0.f;
    for (int e = 0; e < 8; e++) { p[e] = __expf(lg[e] - mx); se += p[e]; }
    float rse = 1.f / se;
    int e0 = 0;
    for (int e = 1; e < 8; e++) if (lg[e] > lg[e0]) e0 = e;        // strict >: first-index tiebreak
    int e1 = (e0 == 0) ? 1 : 0;
    for (int e = 0; e < 8; e++) if (e != e0 && lg[e] > lg[e1]) e1 = e;
    ewflat[2 * t]     = p[e0] * rse;
    ewflat[2 * t + 1] = p[e1] * rse;
    int pa0 = atomicAdd(&counts[e0], 1);
    listAll[e0 * CAP + pa0] = 2 * t;
    int pa1 = atomicAdd(&counts[e1], 1);
    listAll[e1 * CAP + pa1] = 2 * t + 1;
    int p0 = atomicAdd(&counts[8 + e0], 1);
    listK0[e0 * CAP + p0] = 2 * t;
    int p1 = atomicAdd(&counts[16 + e1], 1);
    listK1[e1 * CAP + p1] = 2 * t + 1;
  }
}

// ---------------- gathered-row MFMA GEMM, m97-style 128x128 tile, BK=32 ----------------
// MODE 0: h[a2] = gelu(A[a2>>1] @ w1t^T + b1)            (A = x_f16, K=2048, N=512)
// MODE 1: y[a2>>1] = ew[a2] * (A[a2] @ w2t^T + b2)       (A = h, K=512, N=2048) plain store
// MODE 2: y[a2>>1] += ew[a2] * (A[a2] @ w2t^T + b2)      load-add-store, race-free (1 writer/row)
template <int KDIM, int NDIM, int MODE>
__global__ __launch_bounds__(256) void k_moe_gemm(const f16* __restrict__ A,
                                                  const f16* __restrict__ Bt,
                                                  const float* __restrict__ bias,
                                                  const int* __restrict__ list,
                                                  const int* __restrict__ counts,
                                                  const float* __restrict__ ewflat,
                                                  f16* __restrict__ Hout,
                                                  float* __restrict__ Y) {
  int e = blockIdx.z;
  int cnt = counts[e];
  int mt = blockIdx.y;
  if (mt * 128 >= cnt) return;
  int nt = blockIdx.x;
  int tid = threadIdx.x;
  int lane = tid & 63, wave = tid >> 6;

  __shared__ __align__(16) f16 As[128 * 32];
  __shared__ __align__(16) f16 Bs[128 * 32];
  __shared__ int rowA2[128];
  __shared__ float ews[128];

  if (tid < 128) {
    int slot = mt * 128 + tid;
    int a2 = list[e * CAP + (slot < cnt ? slot : cnt - 1)];
    rowA2[tid] = a2;
    if constexpr (MODE != 0) ews[tid] = ewflat[a2];
  }
  __syncthreads();

  // --- staging setup: chunk c covers LDS bytes [c*1024, +1024), rows c*16..c*16+15 ---
  int sub = lane >> 2;            // row within chunk
  int piece = (lane & 3) * 16;    // byte offset within 64B row-slice
  int arow0 = wave * 16 + sub;        // chunk = wave
  int arow1 = (wave + 4) * 16 + sub;  // chunk = wave+4
  long r0 = (MODE == 0) ? (long)(rowA2[arow0] >> 1) : (long)rowA2[arow0];
  long r1 = (MODE == 0) ? (long)(rowA2[arow1] >> 1) : (long)rowA2[arow1];
  const char* ap0 = (const char*)(A + (size_t)r0 * KDIM) + piece;
  const char* ap1 = (const char*)(A + (size_t)r1 * KDIM) + piece;
  const f16* Be = Bt + (size_t)e * NDIM * KDIM + (size_t)nt * 128 * KDIM;
  const char* bp0 = (const char*)(Be + (size_t)arow0 * KDIM) + piece;
  const char* bp1 = (const char*)(Be + (size_t)arow1 * KDIM) + piece;
  char* asd0 = (char*)As + wave * 1024;
  char* asd1 = (char*)As + (wave + 4) * 1024;
  char* bsd0 = (char*)Bs + wave * 1024;
  char* bsd1 = (char*)Bs + (wave + 4) * 1024;

  f32x4 acc[4][4] = {};
  int wm = wave & 1, wn = wave >> 1;
  int fr = lane & 15, fq = lane >> 4;
  int aoff[4], boff[4];
#pragma unroll
  for (int i = 0; i < 4; i++) {
    aoff[i] = (wm * 64 + i * 16 + fr) * 64 + fq * 16;
    boff[i] = (wn * 64 + i * 16 + fr) * 64 + fq * 16;
  }

  const int nK = KDIM / 32;
  for (int kt = 0; kt < nK; ++kt) {
    int kb = kt * 64;
    __builtin_amdgcn_global_load_lds(AS1C(ap0 + kb), AS3(asd0), 16, 0, 0);
    __builtin_amdgcn_global_load_lds(AS1C(ap1 + kb), AS3(asd1), 16, 0, 0);
    __builtin_amdgcn_global_load_lds(AS1C(bp0 + kb), AS3(bsd0), 16, 0, 0);
    __builtin_amdgcn_global_load_lds(AS1C(bp1 + kb), AS3(bsd1), 16, 0, 0);
    __syncthreads();  // drains vmcnt -> staged data visible
    f16x8 af[4], bf[4];
#pragma unroll
    for (int i = 0; i < 4; i++) af[i] = *(const f16x8*)((const char*)As + aoff[i]);
#pragma unroll
    for (int j = 0; j < 4; j++) bf[j] = *(const f16x8*)((const char*)Bs + boff[j]);
#pragma unroll
    for (int i = 0; i < 4; i++) {
#pragma unroll
      for (int j = 0; j < 4; j++) {
        acc[i][j] = __builtin_amdgcn_mfma_f32_16x16x32_f16(af[i], bf[j], acc[i][j], 0, 0, 0);
      }
    }
    __syncthreads();  // all waves done reading LDS before restage
  }

  // --- epilogue: C/D layout col=lane&15, row=(lane>>4)*4+v ---
#pragma unroll
  for (int i = 0; i < 4; i++) {
#pragma unroll
    for (int j = 0; j < 4; j++) {
      int col = nt * 128 + wn * 64 + j * 16 + fr;
      float bv = bias[e * NDIM + col];
#pragma unroll
      for (int v = 0; v < 4; v++) {
        int sl = wm * 64 + i * 16 + fq * 4 + v;
        int slot = mt * 128 + sl;
        if (slot < cnt) {
          float val = acc[i][j][v] + bv;
          int a2 = rowA2[sl];
          if constexpr (MODE == 0) {
            // gelu_tanh via hardware exp: tanh(z) = 1 - 2/(1+e^{2z})
            float u = val;
            float z = 0.7978845608028654f * (u + 0.044715f * u * u * u);
            float th = 1.f - 2.f / (1.f + __expf(2.f * z));
            Hout[(size_t)a2 * DPROJ + col] = (f16)(0.5f * u * (1.f + th));
          } else if constexpr (MODE == 1) {
            Y[(size_t)(a2 >> 1) * DOUT + col] = val * ews[sl];
          } else {
            float* yp = &Y[(size_t)(a2 >> 1) * DOUT + col];
            *yp = *yp + val * ews[sl];
          }
        }
      }
    }
  }
}

extern "C" void kernel_launch(void* const* d_in, const int* in_sizes, int n_in,
                              void* d_out, int out_size, void* d_ws, size_t ws_size,
                              hipStream_t stream) {
  const float* x  = (const float*)d_in[0];
  const float* gw = (const float*)d_in[1];
  const float* gb = (const float*)d_in[2];
  const float* w1 = (const float*)d_in[3];
  const float* b1 = (const float*)d_in[4];
  const float* w2 = (const float*)d_in[5];
  const float* b2 = (const float*)d_in[6];
  float* y = (float*)d_out;

  char* p = (char*)d_ws;
  f16* xh  = (f16*)p; p += (size_t)TOK * DIN * 2;            // 33.6 MB
  f16* w1t = (f16*)p; p += (size_t)NEXP * DIN * DPROJ * 2;   // 16.8 MB  [e][PROJ][IN]
  f16* w2t = (f16*)p; p += (size_t)NEXP * DPROJ * DOUT * 2;  // 16.8 MB  [e][OUT][PROJ]
  f16* h   = (f16*)p; p += (size_t)TOK * 2 * DPROJ * 2;      // 16.8 MB  rows indexed by a2
  float* ewflat = (float*)p; p += (size_t)TOK * 2 * 4;
  int* listAll  = (int*)p;   p += (size_t)NEXP * CAP * 4;
  int* listK0   = (int*)p;   p += (size_t)NEXP * CAP * 4;
  int* listK1   = (int*)p;   p += (size_t)NEXP * CAP * 4;
  int* counts   = (int*)p;   p += 256;

  hipMemsetAsync(counts, 0, 24 * 4, stream);

  // w1: [E][IN][PROJ] -> w1t [E][PROJ][IN]
  k_transpose<<<dim3(DPROJ / 32, DIN / 32, NEXP), 256, 0, stream>>>(w1, w1t, DIN, DPROJ);
  // w2: [E][PROJ][OUT] -> w2t [E][OUT][PROJ]
  k_transpose<<<dim3(DOUT / 32, DPROJ / 32, NEXP), 256, 0, stream>>>(w2, w2t, DPROJ, DOUT);

  k_route<<<TOK, 256, 0, stream>>>(x, gw, gb, xh, ewflat, listAll, listK0, listK1, counts);

  // GEMM1: h for all assignments
  k_moe_gemm<DIN, DPROJ, 0><<<dim3(DPROJ / 128, TOK / 128, NEXP), 256, 0, stream>>>(
      xh, w1t, b1, listAll, counts, ewflat, h, nullptr);
  // GEMM2 pass A: first-choice -> plain store (covers every y row exactly once)
  k_moe_gemm<DPROJ, DOUT, 1><<<dim3(DOUT / 128, TOK / 128, NEXP), 256, 0, stream>>>(
      h, w2t, b2, listK0, counts + 8, ewflat, nullptr, y);
  // GEMM2 pass B: second-choice -> accumulate (one writer per row, race-free)
  k_moe_gemm<DPROJ, DOUT, 2><<<dim3(DOUT / 128, TOK / 128, NEXP), 256, 0, stream>>>(
      h, w2t, b2, listK1, counts + 16, ewflat, nullptr, y);
}

// Round 3
// 436.927 us; speedup vs baseline: 1.4570x; 1.4570x over previous
//
#include <hip/hip_runtime.h>
#include <hip/hip_fp16.h>
#include <math.h>

#define TOK   8192
#define DIN   2048
#define DOUT  2048
#define DPROJ 512
#define NEXP  8
#define CAP   8192

typedef _Float16 f16;
typedef _Float16 f16x8 __attribute__((ext_vector_type(8)));
typedef float f32x4 __attribute__((ext_vector_type(4)));

#define AS1C(p) ((const __attribute__((address_space(1))) void*)(p))
#define AS3(p)  ((__attribute__((address_space(3))) void*)(p))

// ---------------- transpose + fp32->f16 convert: W[R][C] -> Wt[C][R] ----------------
__global__ __launch_bounds__(256) void k_transpose(const float* __restrict__ W,
                                                   f16* __restrict__ Wt,
                                                   int R, int C) {
  __shared__ f16 tile[32][33];
  size_t eoff = (size_t)blockIdx.z * R * C;
  const float* We = W + eoff;
  f16* Wte = Wt + eoff;
  int r0 = blockIdx.y * 32, c0 = blockIdx.x * 32;
  int lr = threadIdx.x >> 5;   // 0..7
  int lc = threadIdx.x & 31;
#pragma unroll
  for (int i = 0; i < 4; i++) {
    int r = lr * 4 + i;
    tile[r][lc] = (f16)We[(size_t)(r0 + r) * C + c0 + lc];
  }
  __syncthreads();
#pragma unroll
  for (int i = 0; i < 4; i++) {
    int r = lr * 4 + i;  // output row within tile = input column
    Wte[(size_t)(c0 + r) * R + r0 + lc] = tile[lc][r];
  }
}

// ---------------- routing: gate GEMV + softmax + top2; writes choices, NO atomics ----------------
__global__ __launch_bounds__(256) void k_route(const float* __restrict__ x,
                                               const float* __restrict__ gw,
                                               const float* __restrict__ gb,
                                               f16* __restrict__ xh,
                                               float* __restrict__ ewflat,
                                               int* __restrict__ choices) {
  int t = blockIdx.x;
  int tid = threadIdx.x;
  const float* xr = x + (size_t)t * DIN;
  float4 v0 = ((const float4*)xr)[tid * 2];
  float4 v1 = ((const float4*)xr)[tid * 2 + 1];
  float xv[8] = {v0.x, v0.y, v0.z, v0.w, v1.x, v1.y, v1.z, v1.w};
  f16x8 hv;
#pragma unroll
  for (int j = 0; j < 8; j++) hv[j] = (f16)xv[j];
  *(f16x8*)(xh + (size_t)t * DIN + (size_t)tid * 8) = hv;

  float acc[8] = {0.f, 0.f, 0.f, 0.f, 0.f, 0.f, 0.f, 0.f};
  const float4* gr = (const float4*)(gw + (size_t)tid * 8 * NEXP);
#pragma unroll
  for (int j = 0; j < 8; j++) {
    float4 g0 = gr[j * 2], g1 = gr[j * 2 + 1];
    acc[0] += xv[j] * g0.x; acc[1] += xv[j] * g0.y;
    acc[2] += xv[j] * g0.z; acc[3] += xv[j] * g0.w;
    acc[4] += xv[j] * g1.x; acc[5] += xv[j] * g1.y;
    acc[6] += xv[j] * g1.z; acc[7] += xv[j] * g1.w;
  }
#pragma unroll
  for (int off = 32; off > 0; off >>= 1) {
#pragma unroll
    for (int e = 0; e < 8; e++) acc[e] += __shfl_down(acc[e], off, 64);
  }
  __shared__ float wsum[4][8];
  int lane = tid & 63, wave = tid >> 6;
  if (lane == 0) {
#pragma unroll
    for (int e = 0; e < 8; e++) wsum[wave][e] = acc[e];
  }
  __syncthreads();
  if (tid == 0) {
    const float inv = 0.022097086912079608f;  // 1/sqrt(2048)
    float lg[8];
    float mx = -1e30f;
    for (int e = 0; e < 8; e++) {
      lg[e] = (wsum[0][e] + wsum[1][e] + wsum[2][e] + wsum[3][e] + gb[e]) * inv;
      mx = fmaxf(mx, lg[e]);
    }
    float p[8], se = 0.f;
    for (int e = 0; e < 8; e++) { p[e] = __expf(lg[e] - mx); se += p[e]; }
    float rse = 1.f / se;
    int e0 = 0;
    for (int e = 1; e < 8; e++) if (lg[e] > lg[e0]) e0 = e;        // strict >: first-index tiebreak
    int e1 = (e0 == 0) ? 1 : 0;
    for (int e = 0; e < 8; e++) if (e != e0 && lg[e] > lg[e1]) e1 = e;
    ewflat[2 * t]     = p[e0] * rse;
    ewflat[2 * t + 1] = p[e1] * rse;
    choices[t] = e0 | (e1 << 8);
  }
}

// ---------------- list building: per-block LDS histogram, 24 global atomics/block ----------------
// counts layout: [0..7]=all (both choices), [8..15]=first choice, [16..23]=second choice
__global__ __launch_bounds__(256) void k_build(const int* __restrict__ choices,
                                               int* __restrict__ listAll,
                                               int* __restrict__ listK0,
                                               int* __restrict__ listK1,
                                               int* __restrict__ counts) {
  __shared__ int lcnt[24];
  __shared__ int lbase[24];
  int tid = threadIdx.x;
  if (tid < 24) lcnt[tid] = 0;
  __syncthreads();
  int t = blockIdx.x * 256 + tid;
  int ch = choices[t];
  int e0 = ch & 0xff, e1 = (ch >> 8) & 0xff;
  int pA0 = atomicAdd(&lcnt[e0], 1);
  int pA1 = atomicAdd(&lcnt[e1], 1);
  int p0  = atomicAdd(&lcnt[8 + e0], 1);
  int p1  = atomicAdd(&lcnt[16 + e1], 1);
  __syncthreads();
  if (tid < 24) lbase[tid] = atomicAdd(&counts[tid], lcnt[tid]);
  __syncthreads();
  listAll[e0 * CAP + lbase[e0] + pA0]      = 2 * t;
  listAll[e1 * CAP + lbase[e1] + pA1]      = 2 * t + 1;
  listK0[e0 * CAP + lbase[8 + e0] + p0]    = 2 * t;
  listK1[e1 * CAP + lbase[16 + e1] + p1]   = 2 * t + 1;
}

// ---------------- gathered-row MFMA GEMM, m97-style 128x128 tile, BK=32 ----------------
// MODE 0: h[a2] = gelu(A[a2>>1] @ w1t^T + b1)            (A = x_f16, K=2048, N=512)
// MODE 1: y[a2>>1] = ew[a2] * (A[a2] @ w2t^T + b2)       (A = h, K=512, N=2048) plain store
// MODE 2: y[a2>>1] += ew[a2] * (A[a2] @ w2t^T + b2)      load-add-store, race-free (1 writer/row)
template <int KDIM, int NDIM, int MODE>
__global__ __launch_bounds__(256) void k_moe_gemm(const f16* __restrict__ A,
                                                  const f16* __restrict__ Bt,
                                                  const float* __restrict__ bias,
                                                  const int* __restrict__ list,
                                                  const int* __restrict__ counts,
                                                  const float* __restrict__ ewflat,
                                                  f16* __restrict__ Hout,
                                                  float* __restrict__ Y) {
  int e = blockIdx.z;
  int cnt = counts[e];
  int mt = blockIdx.y;
  if (mt * 128 >= cnt) return;
  int nt = blockIdx.x;
  int tid = threadIdx.x;
  int lane = tid & 63, wave = tid >> 6;

  __shared__ __align__(16) f16 As[128 * 32];
  __shared__ __align__(16) f16 Bs[128 * 32];
  __shared__ int rowA2[128];
  __shared__ float ews[128];

  if (tid < 128) {
    int slot = mt * 128 + tid;
    int a2 = list[e * CAP + (slot < cnt ? slot : cnt - 1)];
    rowA2[tid] = a2;
    if constexpr (MODE != 0) ews[tid] = ewflat[a2];
  }
  __syncthreads();

  // --- staging setup: chunk c covers LDS bytes [c*1024, +1024), rows c*16..c*16+15 ---
  int sub = lane >> 2;            // row within chunk
  int piece = (lane & 3) * 16;    // byte offset within 64B row-slice
  int arow0 = wave * 16 + sub;        // chunk = wave
  int arow1 = (wave + 4) * 16 + sub;  // chunk = wave+4
  long r0 = (MODE == 0) ? (long)(rowA2[arow0] >> 1) : (long)rowA2[arow0];
  long r1 = (MODE == 0) ? (long)(rowA2[arow1] >> 1) : (long)rowA2[arow1];
  const char* ap0 = (const char*)(A + (size_t)r0 * KDIM) + piece;
  const char* ap1 = (const char*)(A + (size_t)r1 * KDIM) + piece;
  const f16* Be = Bt + (size_t)e * NDIM * KDIM + (size_t)nt * 128 * KDIM;
  const char* bp0 = (const char*)(Be + (size_t)arow0 * KDIM) + piece;
  const char* bp1 = (const char*)(Be + (size_t)arow1 * KDIM) + piece;
  char* asd0 = (char*)As + wave * 1024;
  char* asd1 = (char*)As + (wave + 4) * 1024;
  char* bsd0 = (char*)Bs + wave * 1024;
  char* bsd1 = (char*)Bs + (wave + 4) * 1024;

  f32x4 acc[4][4] = {};
  int wm = wave & 1, wn = wave >> 1;
  int fr = lane & 15, fq = lane >> 4;
  int aoff[4], boff[4];
#pragma unroll
  for (int i = 0; i < 4; i++) {
    aoff[i] = (wm * 64 + i * 16 + fr) * 64 + fq * 16;
    boff[i] = (wn * 64 + i * 16 + fr) * 64 + fq * 16;
  }

  const int nK = KDIM / 32;
  for (int kt = 0; kt < nK; ++kt) {
    int kb = kt * 64;
    __builtin_amdgcn_global_load_lds(AS1C(ap0 + kb), AS3(asd0), 16, 0, 0);
    __builtin_amdgcn_global_load_lds(AS1C(ap1 + kb), AS3(asd1), 16, 0, 0);
    __builtin_amdgcn_global_load_lds(AS1C(bp0 + kb), AS3(bsd0), 16, 0, 0);
    __builtin_amdgcn_global_load_lds(AS1C(bp1 + kb), AS3(bsd1), 16, 0, 0);
    __syncthreads();  // drains vmcnt -> staged data visible
    f16x8 af[4], bf[4];
#pragma unroll
    for (int i = 0; i < 4; i++) af[i] = *(const f16x8*)((const char*)As + aoff[i]);
#pragma unroll
    for (int j = 0; j < 4; j++) bf[j] = *(const f16x8*)((const char*)Bs + boff[j]);
#pragma unroll
    for (int i = 0; i < 4; i++) {
#pragma unroll
      for (int j = 0; j < 4; j++) {
        acc[i][j] = __builtin_amdgcn_mfma_f32_16x16x32_f16(af[i], bf[j], acc[i][j], 0, 0, 0);
      }
    }
    __syncthreads();  // all waves done reading LDS before restage
  }

  // --- epilogue: C/D layout col=lane&15, row=(lane>>4)*4+v ---
#pragma unroll
  for (int i = 0; i < 4; i++) {
#pragma unroll
    for (int j = 0; j < 4; j++) {
      int col = nt * 128 + wn * 64 + j * 16 + fr;
      float bv = bias[e * NDIM + col];
#pragma unroll
      for (int v = 0; v < 4; v++) {
        int sl = wm * 64 + i * 16 + fq * 4 + v;
        int slot = mt * 128 + sl;
        if (slot < cnt) {
          float val = acc[i][j][v] + bv;
          int a2 = rowA2[sl];
          if constexpr (MODE == 0) {
            // gelu_tanh via hardware exp: tanh(z) = 1 - 2/(1+e^{2z})
            float u = val;
            float z = 0.7978845608028654f * (u + 0.044715f * u * u * u);
            float th = 1.f - 2.f / (1.f + __expf(2.f * z));
            Hout[(size_t)a2 * DPROJ + col] = (f16)(0.5f * u * (1.f + th));
          } else if constexpr (MODE == 1) {
            Y[(size_t)(a2 >> 1) * DOUT + col] = val * ews[sl];
          } else {
            float* yp = &Y[(size_t)(a2 >> 1) * DOUT + col];
            *yp = *yp + val * ews[sl];
          }
        }
      }
    }
  }
}

extern "C" void kernel_launch(void* const* d_in, const int* in_sizes, int n_in,
                              void* d_out, int out_size, void* d_ws, size_t ws_size,
                              hipStream_t stream) {
  const float* x  = (const float*)d_in[0];
  const float* gw = (const float*)d_in[1];
  const float* gb = (const float*)d_in[2];
  const float* w1 = (const float*)d_in[3];
  const float* b1 = (const float*)d_in[4];
  const float* w2 = (const float*)d_in[5];
  const float* b2 = (const float*)d_in[6];
  float* y = (float*)d_out;

  char* p = (char*)d_ws;
  f16* xh  = (f16*)p; p += (size_t)TOK * DIN * 2;            // 33.6 MB
  f16* w1t = (f16*)p; p += (size_t)NEXP * DIN * DPROJ * 2;   // 16.8 MB  [e][PROJ][IN]
  f16* w2t = (f16*)p; p += (size_t)NEXP * DPROJ * DOUT * 2;  // 16.8 MB  [e][OUT][PROJ]
  f16* h   = (f16*)p; p += (size_t)TOK * 2 * DPROJ * 2;      // 16.8 MB  rows indexed by a2
  float* ewflat = (float*)p; p += (size_t)TOK * 2 * 4;
  int* choices  = (int*)p;   p += (size_t)TOK * 4;
  int* listAll  = (int*)p;   p += (size_t)NEXP * CAP * 4;
  int* listK0   = (int*)p;   p += (size_t)NEXP * CAP * 4;
  int* listK1   = (int*)p;   p += (size_t)NEXP * CAP * 4;
  int* counts   = (int*)p;   p += 256;

  hipMemsetAsync(counts, 0, 24 * 4, stream);

  // w1: [E][IN][PROJ] -> w1t [E][PROJ][IN]
  k_transpose<<<dim3(DPROJ / 32, DIN / 32, NEXP), 256, 0, stream>>>(w1, w1t, DIN, DPROJ);
  // w2: [E][PROJ][OUT] -> w2t [E][OUT][PROJ]
  k_transpose<<<dim3(DOUT / 32, DPROJ / 32, NEXP), 256, 0, stream>>>(w2, w2t, DPROJ, DOUT);

  k_route<<<TOK, 256, 0, stream>>>(x, gw, gb, xh, ewflat, choices);
  k_build<<<TOK / 256, 256, 0, stream>>>(choices, listAll, listK0, listK1, counts);

  // GEMM1: h for all assignments
  k_moe_gemm<DIN, DPROJ, 0><<<dim3(DPROJ / 128, TOK / 128, NEXP), 256, 0, stream>>>(
      xh, w1t, b1, listAll, counts, ewflat, h, nullptr);
  // GEMM2 pass A: first-choice -> plain store (covers every y row exactly once)
  k_moe_gemm<DPROJ, DOUT, 1><<<dim3(DOUT / 128, TOK / 128, NEXP), 256, 0, stream>>>(
      h, w2t, b2, listK0, counts + 8, ewflat, nullptr, y);
  // GEMM2 pass B: second-choice -> accumulate (one writer per row, race-free)
  k_moe_gemm<DPROJ, DOUT, 2><<<dim3(DOUT / 128, TOK / 128, NEXP), 256, 0, stream>>>(
      h, w2t, b2, listK1, counts + 16, ewflat, nullptr, y);
}

// Round 4
// 410.807 us; speedup vs baseline: 1.5496x; 1.0636x over previous
//
#include <hip/hip_runtime.h>
#include <hip/hip_fp16.h>
#include <math.h>

#define TOK   8192
#define DIN   2048
#define DOUT  2048
#define DPROJ 512
#define NEXP  8
#define CAP   8192

typedef _Float16 f16;
typedef _Float16 f16x4 __attribute__((ext_vector_type(4)));
typedef _Float16 f16x8 __attribute__((ext_vector_type(8)));
typedef float f32x4 __attribute__((ext_vector_type(4)));

#define AS1C(p) ((const __attribute__((address_space(1))) void*)(p))
#define AS3(p)  ((__attribute__((address_space(3))) void*)(p))

// ---------------- transpose + fp32->f16 convert: W[R][C] -> Wt[C][R] ----------------
__global__ __launch_bounds__(256) void k_transpose(const float* __restrict__ W,
                                                   f16* __restrict__ Wt,
                                                   int R, int C) {
  __shared__ f16 tile[32][33];
  size_t eoff = (size_t)blockIdx.z * R * C;
  const float* We = W + eoff;
  f16* Wte = Wt + eoff;
  int r0 = blockIdx.y * 32, c0 = blockIdx.x * 32;
  int lr = threadIdx.x >> 5;   // 0..7
  int lc = threadIdx.x & 31;
#pragma unroll
  for (int i = 0; i < 4; i++) {
    int r = lr * 4 + i;
    tile[r][lc] = (f16)We[(size_t)(r0 + r) * C + c0 + lc];
  }
  __syncthreads();
#pragma unroll
  for (int i = 0; i < 4; i++) {
    int r = lr * 4 + i;  // output row within tile = input column
    Wte[(size_t)(c0 + r) * R + r0 + lc] = tile[lc][r];
  }
}

// ---------------- fused routing + x->f16 convert: half-wave per token, no LDS/sync ----------------
// Lane c (0..31) of a half-wave handles k = 4c + 128i, i=0..15: coalesced float4 x-load,
// f16x4 store, 8 gw float4 loads (L1-hot 64KB) + 32 FMAs. Butterfly shfl_xor reduce,
// lanes 0/32 do softmax+top2. fp32 x used for selection (numerics unchanged).
__global__ __launch_bounds__(256) void k_route(const float* __restrict__ x,
                                               const float* __restrict__ gw,
                                               const float* __restrict__ gb,
                                               f16* __restrict__ xh,
                                               float* __restrict__ ewflat,
                                               int* __restrict__ choices) {
  int tid = threadIdx.x;
  int lane = tid & 63;
  int half = lane >> 5;    // token within wave
  int c = lane & 31;       // k-chunk
  int wave = tid >> 6;
  int tok = blockIdx.x * 8 + wave * 2 + half;
  const float* xr = x + (size_t)tok * DIN;
  f16* xhr = xh + (size_t)tok * DIN;

  float acc[8] = {0.f, 0.f, 0.f, 0.f, 0.f, 0.f, 0.f, 0.f};
#pragma unroll
  for (int i = 0; i < 16; i++) {
    int k = c * 4 + i * 128;
    float4 xv = *(const float4*)(xr + k);
    f16x4 hv = {(f16)xv.x, (f16)xv.y, (f16)xv.z, (f16)xv.w};
    *(f16x4*)(xhr + k) = hv;
    const float4* g = (const float4*)(gw + (size_t)k * NEXP);
    float4 g0 = g[0], g1 = g[1], g2 = g[2], g3 = g[3];
    float4 g4 = g[4], g5 = g[5], g6 = g[6], g7 = g[7];
    acc[0] += xv.x * g0.x + xv.y * g2.x + xv.z * g4.x + xv.w * g6.x;
    acc[1] += xv.x * g0.y + xv.y * g2.y + xv.z * g4.y + xv.w * g6.y;
    acc[2] += xv.x * g0.z + xv.y * g2.z + xv.z * g4.z + xv.w * g6.z;
    acc[3] += xv.x * g0.w + xv.y * g2.w + xv.z * g4.w + xv.w * g6.w;
    acc[4] += xv.x * g1.x + xv.y * g3.x + xv.z * g5.x + xv.w * g7.x;
    acc[5] += xv.x * g1.y + xv.y * g3.y + xv.z * g5.y + xv.w * g7.y;
    acc[6] += xv.x * g1.z + xv.y * g3.z + xv.z * g5.z + xv.w * g7.z;
    acc[7] += xv.x * g1.w + xv.y * g3.w + xv.z * g5.w + xv.w * g7.w;
  }
  // butterfly reduce within each 32-lane half (masks < 32 stay inside the half)
#pragma unroll
  for (int m = 1; m <= 16; m <<= 1) {
#pragma unroll
    for (int e = 0; e < 8; e++) acc[e] += __shfl_xor(acc[e], m, 64);
  }
  if (c == 0) {
    const float inv = 0.022097086912079608f;  // 1/sqrt(2048)
    float lg[8];
    float mx = -1e30f;
#pragma unroll
    for (int e = 0; e < 8; e++) {
      lg[e] = (acc[e] + gb[e]) * inv;
      mx = fmaxf(mx, lg[e]);
    }
    float p[8], se = 0.f;
#pragma unroll
    for (int e = 0; e < 8; e++) { p[e] = __expf(lg[e] - mx); se += p[e]; }
    float rse = 1.f / se;
    int e0 = 0;
#pragma unroll
    for (int e = 1; e < 8; e++) if (lg[e] > lg[e0]) e0 = e;  // strict >: first-index tiebreak
    int e1 = (e0 == 0) ? 1 : 0;
#pragma unroll
    for (int e = 0; e < 8; e++) if (e != e0 && lg[e] > lg[e1]) e1 = e;
    ewflat[2 * tok]     = p[e0] * rse;
    ewflat[2 * tok + 1] = p[e1] * rse;
    choices[tok] = e0 | (e1 << 8);
  }
}

// ---------------- list building: per-block LDS histogram, 24 global atomics/block ----------------
// counts layout: [0..7]=all (both choices), [8..15]=first choice, [16..23]=second choice
__global__ __launch_bounds__(256) void k_build(const int* __restrict__ choices,
                                               int* __restrict__ listAll,
                                               int* __restrict__ listK0,
                                               int* __restrict__ listK1,
                                               int* __restrict__ counts) {
  __shared__ int lcnt[24];
  __shared__ int lbase[24];
  int tid = threadIdx.x;
  if (tid < 24) lcnt[tid] = 0;
  __syncthreads();
  int t = blockIdx.x * 256 + tid;
  int ch = choices[t];
  int e0 = ch & 0xff, e1 = (ch >> 8) & 0xff;
  int pA0 = atomicAdd(&lcnt[e0], 1);
  int pA1 = atomicAdd(&lcnt[e1], 1);
  int p0  = atomicAdd(&lcnt[8 + e0], 1);
  int p1  = atomicAdd(&lcnt[16 + e1], 1);
  __syncthreads();
  if (tid < 24) lbase[tid] = atomicAdd(&counts[tid], lcnt[tid]);
  __syncthreads();
  listAll[e0 * CAP + lbase[e0] + pA0]      = 2 * t;
  listAll[e1 * CAP + lbase[e1] + pA1]      = 2 * t + 1;
  listK0[e0 * CAP + lbase[8 + e0] + p0]    = 2 * t;
  listK1[e1 * CAP + lbase[16 + e1] + p1]   = 2 * t + 1;
}

// ---------------- gathered-row MFMA GEMM, m97-style 128x128 tile, BK=32 ----------------
// MODE 0: h[a2] = gelu(A[a2>>1] @ w1t^T + b1)            (A = x_f16, K=2048, N=512)
// MODE 1: y[a2>>1] = ew[a2] * (A[a2] @ w2t^T + b2)       (A = h, K=512, N=2048) plain store
// MODE 2: y[a2>>1] += ew[a2] * (A[a2] @ w2t^T + b2)      load-add-store, race-free (1 writer/row)
template <int KDIM, int NDIM, int MODE>
__global__ __launch_bounds__(256) void k_moe_gemm(const f16* __restrict__ A,
                                                  const f16* __restrict__ Bt,
                                                  const float* __restrict__ bias,
                                                  const int* __restrict__ list,
                                                  const int* __restrict__ counts,
                                                  const float* __restrict__ ewflat,
                                                  f16* __restrict__ Hout,
                                                  float* __restrict__ Y) {
  int e = blockIdx.z;
  int cnt = counts[e];
  int mt = blockIdx.y;
  if (mt * 128 >= cnt) return;
  int nt = blockIdx.x;
  int tid = threadIdx.x;
  int lane = tid & 63, wave = tid >> 6;

  __shared__ __align__(16) f16 As[128 * 32];
  __shared__ __align__(16) f16 Bs[128 * 32];
  __shared__ int rowA2[128];
  __shared__ float ews[128];

  if (tid < 128) {
    int slot = mt * 128 + tid;
    int a2 = list[e * CAP + (slot < cnt ? slot : cnt - 1)];
    rowA2[tid] = a2;
    if constexpr (MODE != 0) ews[tid] = ewflat[a2];
  }
  __syncthreads();

  // --- staging setup: chunk c covers LDS bytes [c*1024, +1024), rows c*16..c*16+15 ---
  int sub = lane >> 2;            // row within chunk
  int piece = (lane & 3) * 16;    // byte offset within 64B row-slice
  int arow0 = wave * 16 + sub;        // chunk = wave
  int arow1 = (wave + 4) * 16 + sub;  // chunk = wave+4
  long r0 = (MODE == 0) ? (long)(rowA2[arow0] >> 1) : (long)rowA2[arow0];
  long r1 = (MODE == 0) ? (long)(rowA2[arow1] >> 1) : (long)rowA2[arow1];
  const char* ap0 = (const char*)(A + (size_t)r0 * KDIM) + piece;
  const char* ap1 = (const char*)(A + (size_t)r1 * KDIM) + piece;
  const f16* Be = Bt + (size_t)e * NDIM * KDIM + (size_t)nt * 128 * KDIM;
  const char* bp0 = (const char*)(Be + (size_t)arow0 * KDIM) + piece;
  const char* bp1 = (const char*)(Be + (size_t)arow1 * KDIM) + piece;
  char* asd0 = (char*)As + wave * 1024;
  char* asd1 = (char*)As + (wave + 4) * 1024;
  char* bsd0 = (char*)Bs + wave * 1024;
  char* bsd1 = (char*)Bs + (wave + 4) * 1024;

  f32x4 acc[4][4] = {};
  int wm = wave & 1, wn = wave >> 1;
  int fr = lane & 15, fq = lane >> 4;
  int aoff[4], boff[4];
#pragma unroll
  for (int i = 0; i < 4; i++) {
    aoff[i] = (wm * 64 + i * 16 + fr) * 64 + fq * 16;
    boff[i] = (wn * 64 + i * 16 + fr) * 64 + fq * 16;
  }

  const int nK = KDIM / 32;
  for (int kt = 0; kt < nK; ++kt) {
    int kb = kt * 64;
    __builtin_amdgcn_global_load_lds(AS1C(ap0 + kb), AS3(asd0), 16, 0, 0);
    __builtin_amdgcn_global_load_lds(AS1C(ap1 + kb), AS3(asd1), 16, 0, 0);
    __builtin_amdgcn_global_load_lds(AS1C(bp0 + kb), AS3(bsd0), 16, 0, 0);
    __builtin_amdgcn_global_load_lds(AS1C(bp1 + kb), AS3(bsd1), 16, 0, 0);
    __syncthreads();  // drains vmcnt -> staged data visible
    f16x8 af[4], bf[4];
#pragma unroll
    for (int i = 0; i < 4; i++) af[i] = *(const f16x8*)((const char*)As + aoff[i]);
#pragma unroll
    for (int j = 0; j < 4; j++) bf[j] = *(const f16x8*)((const char*)Bs + boff[j]);
#pragma unroll
    for (int i = 0; i < 4; i++) {
#pragma unroll
      for (int j = 0; j < 4; j++) {
        acc[i][j] = __builtin_amdgcn_mfma_f32_16x16x32_f16(af[i], bf[j], acc[i][j], 0, 0, 0);
      }
    }
    __syncthreads();  // all waves done reading LDS before restage
  }

  // --- epilogue: C/D layout col=lane&15, row=(lane>>4)*4+v ---
#pragma unroll
  for (int i = 0; i < 4; i++) {
#pragma unroll
    for (int j = 0; j < 4; j++) {
      int col = nt * 128 + wn * 64 + j * 16 + fr;
      float bv = bias[e * NDIM + col];
#pragma unroll
      for (int v = 0; v < 4; v++) {
        int sl = wm * 64 + i * 16 + fq * 4 + v;
        int slot = mt * 128 + sl;
        if (slot < cnt) {
          float val = acc[i][j][v] + bv;
          int a2 = rowA2[sl];
          if constexpr (MODE == 0) {
            // gelu_tanh via hardware exp: tanh(z) = 1 - 2/(1+e^{2z})
            float u = val;
            float z = 0.7978845608028654f * (u + 0.044715f * u * u * u);
            float th = 1.f - 2.f / (1.f + __expf(2.f * z));
            Hout[(size_t)a2 * DPROJ + col] = (f16)(0.5f * u * (1.f + th));
          } else if constexpr (MODE == 1) {
            Y[(size_t)(a2 >> 1) * DOUT + col] = val * ews[sl];
          } else {
            float* yp = &Y[(size_t)(a2 >> 1) * DOUT + col];
            *yp = *yp + val * ews[sl];
          }
        }
      }
    }
  }
}

extern "C" void kernel_launch(void* const* d_in, const int* in_sizes, int n_in,
                              void* d_out, int out_size, void* d_ws, size_t ws_size,
                              hipStream_t stream) {
  const float* x  = (const float*)d_in[0];
  const float* gw = (const float*)d_in[1];
  const float* gb = (const float*)d_in[2];
  const float* w1 = (const float*)d_in[3];
  const float* b1 = (const float*)d_in[4];
  const float* w2 = (const float*)d_in[5];
  const float* b2 = (const float*)d_in[6];
  float* y = (float*)d_out;

  char* p = (char*)d_ws;
  f16* xh  = (f16*)p; p += (size_t)TOK * DIN * 2;            // 33.6 MB
  f16* w1t = (f16*)p; p += (size_t)NEXP * DIN * DPROJ * 2;   // 16.8 MB  [e][PROJ][IN]
  f16* w2t = (f16*)p; p += (size_t)NEXP * DPROJ * DOUT * 2;  // 16.8 MB  [e][OUT][PROJ]
  f16* h   = (f16*)p; p += (size_t)TOK * 2 * DPROJ * 2;      // 16.8 MB  rows indexed by a2
  float* ewflat = (float*)p; p += (size_t)TOK * 2 * 4;
  int* choices  = (int*)p;   p += (size_t)TOK * 4;
  int* listAll  = (int*)p;   p += (size_t)NEXP * CAP * 4;
  int* listK0   = (int*)p;   p += (size_t)NEXP * CAP * 4;
  int* listK1   = (int*)p;   p += (size_t)NEXP * CAP * 4;
  int* counts   = (int*)p;   p += 256;

  hipMemsetAsync(counts, 0, 24 * 4, stream);

  // w1: [E][IN][PROJ] -> w1t [E][PROJ][IN]
  k_transpose<<<dim3(DPROJ / 32, DIN / 32, NEXP), 256, 0, stream>>>(w1, w1t, DIN, DPROJ);
  // w2: [E][PROJ][OUT] -> w2t [E][OUT][PROJ]
  k_transpose<<<dim3(DOUT / 32, DPROJ / 32, NEXP), 256, 0, stream>>>(w2, w2t, DPROJ, DOUT);

  k_route<<<TOK / 8, 256, 0, stream>>>(x, gw, gb, xh, ewflat, choices);
  k_build<<<TOK / 256, 256, 0, stream>>>(choices, listAll, listK0, listK1, counts);

  // GEMM1: h for all assignments
  k_moe_gemm<DIN, DPROJ, 0><<<dim3(DPROJ / 128, TOK / 128, NEXP), 256, 0, stream>>>(
      xh, w1t, b1, listAll, counts, ewflat, h, nullptr);
  // GEMM2 pass A: first-choice -> plain store (covers every y row exactly once)
  k_moe_gemm<DPROJ, DOUT, 1><<<dim3(DOUT / 128, TOK / 128, NEXP), 256, 0, stream>>>(
      h, w2t, b2, listK0, counts + 8, ewflat, nullptr, y);
  // GEMM2 pass B: second-choice -> accumulate (one writer per row, race-free)
  k_moe_gemm<DPROJ, DOUT, 2><<<dim3(DOUT / 128, TOK / 128, NEXP), 256, 0, stream>>>(
      h, w2t, b2, listK1, counts + 16, ewflat, nullptr, y);
}